// Round 14
// baseline (182.313 us; speedup 1.0000x reference)
//
#include <hip/hip_runtime.h>
#include <hip/hip_bf16.h>
#include <math.h>

#define N_NODES 100000
#define N_EDGES 1600000
#define D 64
#define TWO_D 128
#define LN_EPS 1e-5f

#define BSHIFT 7                                   // 128 nodes per bucket
#define BMASK 127
#define NBUCK ((N_NODES + 127) >> BSHIFT)          // 782
#define BCAP 4096                                  // per-bucket CSR capacity (mean 2046, +45 sigma)
#define EPB 4096                                   // edges per bscat block
#define NEB ((N_EDGES + EPB - 1) / EPB)            // 391
#define BOFS_STRIDE (NBUCK + 1)
#define NTILES ((N_NODES + 63) / 64)               // 1563
#define XQ (N_NODES * D / 4)                       // float4 count for x cvt
#define WELEMS (3 * 4 * 4 * 64 * 8)                // Wperm element count
#define CVT_BLOCKS ((XQ + WELEMS + 1023) / 1024)   // 1587

typedef __attribute__((ext_vector_type(4))) float f32x4;
typedef __attribute__((ext_vector_type(8))) _Float16 h16x8;
typedef __attribute__((ext_vector_type(8))) unsigned short u16x8;

__device__ __forceinline__ unsigned short f2h(float f) {
    return __builtin_bit_cast(unsigned short, (_Float16)f);   // RNE
}
// fp16 packed max on u16 storage (v_pk_max_f16; data is NaN-free).
__device__ __forceinline__ u16x8 pkmaxh(u16x8 a, u16x8 b) {
    return __builtin_bit_cast(u16x8,
        __builtin_elementwise_max(__builtin_bit_cast(h16x8, a),
                                  __builtin_bit_cast(h16x8, b)));
}

// ---------------------------------------------------------------------------
// setup: union grid. Blocks [0, NEB) run bscat (per-block LDS sort by bucket,
// EPB=4096 -> 391 blocks fills all CUs); blocks [NEB, ..) run the fp16
// converters concurrently (cvt hides behind bscat).
// Edge record packed to int32: (src << 7) | (dst & 127); src < 2^17.
// ---------------------------------------------------------------------------
__global__ __launch_bounds__(1024) void setup_kernel(const int* __restrict__ src,
                                                     const int* __restrict__ dst,
                                                     int* __restrict__ ebuf,
                                                     int* __restrict__ bofs,
                                                     const float* __restrict__ xf,
                                                     const float* __restrict__ Ws,
                                                     ushort* __restrict__ xb,
                                                     ushort* __restrict__ Wperm) {
    if (blockIdx.x < NEB) {
        __shared__ int cnt[NBUCK];
        __shared__ int off[NBUCK];
        __shared__ int stage[EPB];
        const int e0 = blockIdx.x * EPB;
        const int nE = min(EPB, N_EDGES - e0);
        int d[4], s[4];

        for (int i = threadIdx.x; i < NBUCK; i += 1024) cnt[i] = 0;
        __syncthreads();
#pragma unroll
        for (int k = 0; k < 4; ++k) {
            const int i = threadIdx.x + k * 1024;
            if (i < nE) {
                d[k] = dst[e0 + i];
                s[k] = src[e0 + i];
                atomicAdd(&cnt[d[k] >> BSHIFT], 1);
            }
        }
        __syncthreads();
        // Hillis-Steele inclusive scan over NBUCK (<1024)
        const int v = (threadIdx.x < NBUCK) ? cnt[threadIdx.x] : 0;
        if (threadIdx.x < NBUCK) off[threadIdx.x] = v;
        __syncthreads();
        for (int o = 1; o < 1024; o <<= 1) {
            int t = 0;
            if (threadIdx.x < NBUCK && threadIdx.x >= o) t = off[threadIdx.x - o];
            __syncthreads();
            if (threadIdx.x < NBUCK) off[threadIdx.x] += t;
            __syncthreads();
        }
        if (threadIdx.x < NBUCK) {
            const int ex = off[threadIdx.x] - v;      // exclusive
            bofs[blockIdx.x * BOFS_STRIDE + threadIdx.x] = ex;
            off[threadIdx.x] = ex;
            cnt[threadIdx.x] = 0;
        }
        if (threadIdx.x == 0) bofs[blockIdx.x * BOFS_STRIDE + NBUCK] = nE;
        __syncthreads();
#pragma unroll
        for (int k = 0; k < 4; ++k) {
            const int i = threadIdx.x + k * 1024;
            if (i < nE) {
                const int b = d[k] >> BSHIFT;
                const int r = atomicAdd(&cnt[b], 1);
                stage[off[b] + r] = (s[k] << BSHIFT) | (d[k] & BMASK);
            }
        }
        __syncthreads();
        for (int i = threadIdx.x; i < nE; i += 1024)
            ebuf[e0 + i] = stage[i];
    } else {
        const int i = (blockIdx.x - NEB) * 1024 + threadIdx.x;
        if (i < XQ) {
            float4 v = ((const float4*)xf)[i];
            ushort4 o;
            o.x = f2h(v.x); o.y = f2h(v.y); o.z = f2h(v.z); o.w = f2h(v.w);
            ((ushort4*)xb)[i] = o;
        } else {
            const int k = i - XQ;
            if (k < WELEMS) {
                int j    = k & 7;
                int lane = (k >> 3) & 63;
                int c    = (k >> 9) & 3;
                int s    = (k >> 11) & 3;
                int lay  = k >> 13;
                int kk = 32 * s + 8 * (lane >> 4) + j;
                int dd = 16 * c + (lane & 15);
                Wperm[k] = f2h(Ws[((size_t)lay * TWO_D + kk) * D + dd]);
            }
        }
    }
}

// ---------------------------------------------------------------------------
// bbuild: one block per bucket (512 threads). DENSE run gather: each thread
// owns output positions pos, pos+512, ... and binary-searches rdst[] to find
// its run -> all ~2046 loads in flight. LDS counting sort -> padded CSR +
// degree-balanced pairs (fused bitonic per 64-node tile).
// ---------------------------------------------------------------------------
__global__ __launch_bounds__(512) void bbuild_kernel(const int* __restrict__ ebuf,
                                                     const int* __restrict__ bofs,
                                                     int* __restrict__ row_ptr,
                                                     int* __restrict__ deg,
                                                     int* __restrict__ ssrc,
                                                     ushort* __restrict__ pairs) {
    __shared__ int rst[NEB], rlen[NEB], rdst[NEB];
    __shared__ int stage[BCAP];
    __shared__ int stage2[BCAP];
    __shared__ int cnt[128], excl[128];
    const int b = blockIdx.x;
    const int nb0 = b << BSHIFT;

    for (int i = threadIdx.x; i < NEB; i += 512) {
        const int st = bofs[i * BOFS_STRIDE + b];
        const int en = bofs[i * BOFS_STRIDE + b + 1];
        rst[i] = st; rlen[i] = en - st;
    }
    __syncthreads();
    // scan rlen -> rdst (inclusive), NEB=391 < 512
    const int rv = (threadIdx.x < NEB) ? rlen[threadIdx.x] : 0;
    if (threadIdx.x < NEB) rdst[threadIdx.x] = rv;
    __syncthreads();
    for (int o = 1; o < 512; o <<= 1) {
        int t = 0;
        if (threadIdx.x < NEB && threadIdx.x >= o) t = rdst[threadIdx.x - o];
        __syncthreads();
        if (threadIdx.x < NEB) rdst[threadIdx.x] += t;
        __syncthreads();
    }
    const int total = rdst[NEB - 1];

    // dense gather: binary search run for each output position
    for (int pos = threadIdx.x; pos < total; pos += 512) {
        int lo = 0, hi = NEB - 1;
        while (lo < hi) {                       // first run with rdst[run] > pos
            const int mid = (lo + hi) >> 1;
            if (rdst[mid] <= pos) lo = mid + 1; else hi = mid;
        }
        const int doff = rdst[lo] - rlen[lo];
        stage[pos] = ebuf[lo * EPB + rst[lo] + (pos - doff)];
    }
    if (threadIdx.x < 128) cnt[threadIdx.x] = 0;
    __syncthreads();

    // counting sort by node-within-bucket
    for (int i = threadIdx.x; i < total; i += 512)
        atomicAdd(&cnt[stage[i] & BMASK], 1);
    __syncthreads();
    const int cv = (threadIdx.x < 128) ? cnt[threadIdx.x] : 0;
    if (threadIdx.x < 128) excl[threadIdx.x] = cv;
    __syncthreads();
    for (int o = 1; o < 128; o <<= 1) {
        int t = 0;
        if (threadIdx.x < 128 && threadIdx.x >= o) t = excl[threadIdx.x - o];
        __syncthreads();
        if (threadIdx.x < 128) excl[threadIdx.x] += t;
        __syncthreads();
    }
    const int lane = threadIdx.x & 63;
    if (threadIdx.x < 128) {
        excl[threadIdx.x] -= cv;              // exclusive
        const int node = nb0 + threadIdx.x;
        if (node < N_NODES) {
            row_ptr[node] = b * BCAP + excl[threadIdx.x];
            deg[node] = cv;
        }
        cnt[threadIdx.x] = 0;
    }

    // fused dbal: bitonic-sort each 64-node tile by degree, pair g <-> 63-g.
    if (threadIdx.x < 128) {
        const int tile = 2 * b + (threadIdx.x >> 6);
        if (tile < NTILES) {
            int key = (cv << 6) | lane;
#pragma unroll
            for (int k = 2; k <= 64; k <<= 1) {
#pragma unroll
                for (int jj = k >> 1; jj > 0; jj >>= 1) {
                    const int other = __shfl_xor(key, jj, 64);
                    const bool up = ((lane & k) == 0);
                    const bool lower = ((lane & jj) == 0);
                    key = (lower == up) ? min(key, other) : max(key, other);
                }
            }
            const int small_nl = key & 63;
            const int big_nl = __shfl(key, 63 - lane, 64) & 63;
            if (lane < 32)
                pairs[tile * 32 + lane] = (ushort)((big_nl << 6) | small_nl);
        }
    }
    __syncthreads();

    for (int i = threadIdx.x; i < total; i += 512) {
        const int p = stage[i];
        const int dl = p & BMASK;
        const int r = atomicAdd(&cnt[dl], 1);
        stage2[excl[dl] + r] = p >> BSHIFT;
    }
    __syncthreads();
    for (int i = threadIdx.x; i < total; i += 512)
        ssrc[b * BCAP + i] = stage2[i];
}

// ---------------------------------------------------------------------------
// Cross-node pipelined pair gather: walks [A's edges][B's edges] as one
// virtual sequence with node-boundary-aligned batches. The lookahead quad
// crosses the A->B boundary, so the load pipeline never drains mid-pair.
// Two statically-targeted loops (mA, then mB) keep accumulator selection
// compile-time. Clamped duplicate loads in short batches are idempotent.
// ---------------------------------------------------------------------------
__device__ __forceinline__ void gather_pair(const u16x8* __restrict__ x8,
                                            const int* __restrict__ ssrc,
                                            int fl, int base,
                                            int begA, int dA, int begB, int dB,
                                            u16x8& mA, u16x8& mB)
{
    const int total = dA + dB;
    if (total <= 0) return;

    int j = 0;
    int cnt = (dA > 0) ? min(8, dA) : min(8, total);
    {
        const int v = j + min(fl, cnt - 1);
        const int p = (v < dA) ? begA + v : begB + (v - dA);
        int idx = ssrc[p];

        int s0 = __shfl(idx, base, 64);
        int s1 = __shfl(idx, base + min(1, cnt - 1), 64);
        int s2 = __shfl(idx, base + min(2, cnt - 1), 64);
        int s3 = __shfl(idx, base + min(3, cnt - 1), 64);
        u16x8 a0 = x8[s0 * 8 + fl];
        u16x8 a1 = x8[s1 * 8 + fl];
        u16x8 a2 = x8[s2 * 8 + fl];
        u16x8 a3 = x8[s3 * 8 + fl];

        // ---- phase A: batches in A's range ----
        while (j < dA) {
            int s4 = __shfl(idx, base + min(4, cnt - 1), 64);
            int s5 = __shfl(idx, base + min(5, cnt - 1), 64);
            int s6 = __shfl(idx, base + min(6, cnt - 1), 64);
            int s7 = __shfl(idx, base + min(7, cnt - 1), 64);
            u16x8 b0 = x8[s4 * 8 + fl];
            u16x8 b1 = x8[s5 * 8 + fl];
            u16x8 b2 = x8[s6 * 8 + fl];
            u16x8 b3 = x8[s7 * 8 + fl];

            const int nj = j + cnt;
            const bool more = nj < total;
            int ncnt = cnt, nidx = idx;
            if (more) {
                ncnt = (nj < dA) ? min(8, dA - nj) : min(8, total - nj);
                const int nv = nj + min(fl, ncnt - 1);
                nidx = ssrc[(nv < dA) ? begA + nv : begB + (nv - dA)];
            }

            mA = pkmaxh(mA, pkmaxh(pkmaxh(a0, a1), pkmaxh(a2, a3)));

            if (more) {
                int u0 = __shfl(nidx, base, 64);
                int u1 = __shfl(nidx, base + min(1, ncnt - 1), 64);
                int u2 = __shfl(nidx, base + min(2, ncnt - 1), 64);
                int u3 = __shfl(nidx, base + min(3, ncnt - 1), 64);
                a0 = x8[u0 * 8 + fl];
                a1 = x8[u1 * 8 + fl];
                a2 = x8[u2 * 8 + fl];
                a3 = x8[u3 * 8 + fl];
            }

            mA = pkmaxh(mA, pkmaxh(pkmaxh(b0, b1), pkmaxh(b2, b3)));
            j = nj; cnt = ncnt; idx = nidx;
        }

        // ---- phase B: batches in B's range (pipeline state carries over) ----
        while (j < total) {
            int s4 = __shfl(idx, base + min(4, cnt - 1), 64);
            int s5 = __shfl(idx, base + min(5, cnt - 1), 64);
            int s6 = __shfl(idx, base + min(6, cnt - 1), 64);
            int s7 = __shfl(idx, base + min(7, cnt - 1), 64);
            u16x8 b0 = x8[s4 * 8 + fl];
            u16x8 b1 = x8[s5 * 8 + fl];
            u16x8 b2 = x8[s6 * 8 + fl];
            u16x8 b3 = x8[s7 * 8 + fl];

            const int nj = j + cnt;
            const bool more = nj < total;
            int ncnt = cnt, nidx = idx;
            if (more) {
                ncnt = min(8, total - nj);
                const int nv = nj + min(fl, ncnt - 1);
                nidx = ssrc[begB + (nv - dA)];
            }

            mB = pkmaxh(mB, pkmaxh(pkmaxh(a0, a1), pkmaxh(a2, a3)));

            if (more) {
                int u0 = __shfl(nidx, base, 64);
                int u1 = __shfl(nidx, base + min(1, ncnt - 1), 64);
                int u2 = __shfl(nidx, base + min(2, ncnt - 1), 64);
                int u3 = __shfl(nidx, base + min(3, ncnt - 1), 64);
                a0 = x8[u0 * 8 + fl];
                a1 = x8[u1 * 8 + fl];
                a2 = x8[u2 * 8 + fl];
                a3 = x8[u3 * 8 + fl];
            }

            mB = pkmaxh(mB, pkmaxh(pkmaxh(b0, b1), pkmaxh(b2, b3)));
            j = nj; cnt = ncnt; idx = nidx;
        }
    }
}

// ---------------------------------------------------------------------------
// Fused layer (fp16): 64 nodes per 256-thread block; degree-balanced pairs;
// cross-node pipelined gather; MFMA GEMM + bias + LN + ELU.
// ---------------------------------------------------------------------------
__global__ __launch_bounds__(256, 8) void layer_kernel(
    const ushort* __restrict__ xb,      // fp16 bits
    const int* __restrict__ row_ptr,
    const int* __restrict__ deg,
    const int* __restrict__ ssrc,
    const ushort* __restrict__ pairs,
    const ushort* __restrict__ Wperm,   // this layer's [4][4][64][8] fp16
    const float* __restrict__ bias,
    const float* __restrict__ gamma,
    const float* __restrict__ beta,
    ushort* __restrict__ out_b,         // fp16 out (layers 0,1) or nullptr
    float*  __restrict__ out_f)         // f32 out (layer 2) or nullptr
{
    __shared__ u16x8 xt[64][8];
    __shared__ u16x8 at[64][8];

    const int tid = threadIdx.x;
    const int fl = tid & 7;
    const int base = tid & 56;                 // 8-lane group base within wave
    const int grp = tid >> 3;                  // 0..31
    const u16x8* __restrict__ x8 = (const u16x8*)xb;
    const int nblk0 = blockIdx.x * 64;

    const int pr = pairs[blockIdx.x * 32 + grp];
    const int nlA = pr & 63, nlB = (pr >> 6) & 63;
    const int nodeA = nblk0 + nlA, nodeB = nblk0 + nlB;
    const bool vA = nodeA < N_NODES, vB = nodeB < N_NODES;

    int begA = 0, dA = 0, begB = 0, dB = 0;
    if (vA) { begA = row_ptr[nodeA]; dA = deg[nodeA]; }
    if (vB) { begB = row_ptr[nodeB]; dB = deg[nodeB]; }

    u16x8 mA, mB;
#pragma unroll
    for (int e = 0; e < 8; ++e) { mA[e] = 0xFC00; mB[e] = 0xFC00; }   // -inf
    gather_pair(x8, ssrc, fl, base, begA, dA, begB, dB, mA, mB);

    if (vA) {
        const u16x8 xs = x8[nodeA * 8 + fl];
        u16x8 o;
        if (dA > 0) {
            h16x8 dd = __builtin_bit_cast(h16x8, mA) - __builtin_bit_cast(h16x8, xs);
            h16x8 zz = 0;
            o = __builtin_bit_cast(u16x8, __builtin_elementwise_max(dd, zz));
        } else {
#pragma unroll
            for (int e = 0; e < 8; ++e) o[e] = 0;
        }
        const int slot = fl ^ (nlA & 7);
        xt[nlA][slot] = xs;
        at[nlA][slot] = o;
    }
    if (vB) {
        const u16x8 xs = x8[nodeB * 8 + fl];
        u16x8 o;
        if (dB > 0) {
            h16x8 dd = __builtin_bit_cast(h16x8, mB) - __builtin_bit_cast(h16x8, xs);
            h16x8 zz = 0;
            o = __builtin_bit_cast(u16x8, __builtin_elementwise_max(dd, zz));
        } else {
#pragma unroll
            for (int e = 0; e < 8; ++e) o[e] = 0;
        }
        const int slot = fl ^ (nlB & 7);
        xt[nlB][slot] = xs;
        at[nlB][slot] = o;
    }
    __syncthreads();

    // --- GEMM phase: wave per 16 nodes ---
    const int wave = tid >> 6;
    const int lane = tid & 63;
    const int n0 = nblk0 + wave * 16;
    if (n0 >= N_NODES) return;
    const int row = lane & 15;
    const int kb  = lane >> 4;
    const int nl  = wave * 16 + row;
    const int sw  = nl & 7;

    h16x8 a0 = __builtin_bit_cast(h16x8, xt[nl][kb ^ sw]);
    h16x8 a1 = __builtin_bit_cast(h16x8, xt[nl][(kb + 4) ^ sw]);
    h16x8 a2 = __builtin_bit_cast(h16x8, at[nl][kb ^ sw]);
    h16x8 a3 = __builtin_bit_cast(h16x8, at[nl][(kb + 4) ^ sw]);

    const h16x8* __restrict__ wp = (const h16x8*)Wperm;
    h16x8 wf[4][4];
#pragma unroll
    for (int s = 0; s < 4; ++s)
#pragma unroll
        for (int c = 0; c < 4; ++c)
            wf[s][c] = wp[(s * 4 + c) * 64 + lane];

    f32x4 acc[4];
#pragma unroll
    for (int c = 0; c < 4; ++c) acc[c] = (f32x4){0.f, 0.f, 0.f, 0.f};
#pragma unroll
    for (int c = 0; c < 4; ++c) {
        acc[c] = __builtin_amdgcn_mfma_f32_16x16x32_f16(a0, wf[0][c], acc[c], 0, 0, 0);
        acc[c] = __builtin_amdgcn_mfma_f32_16x16x32_f16(a1, wf[1][c], acc[c], 0, 0, 0);
        acc[c] = __builtin_amdgcn_mfma_f32_16x16x32_f16(a2, wf[2][c], acc[c], 0, 0, 0);
        acc[c] = __builtin_amdgcn_mfma_f32_16x16x32_f16(a3, wf[3][c], acc[c], 0, 0, 0);
    }

    float bv[4], gv[4], btv[4];
#pragma unroll
    for (int c = 0; c < 4; ++c) {
        const int col = 16 * c + row;
        bv[c] = bias[col]; gv[c] = gamma[col]; btv[c] = beta[col];
    }

#pragma unroll
    for (int j = 0; j < 4; ++j) {
        float h0 = acc[0][j] + bv[0];
        float h1 = acc[1][j] + bv[1];
        float h2 = acc[2][j] + bv[2];
        float h3 = acc[3][j] + bv[3];
        float ps = (h0 + h1) + (h2 + h3);
        ps += __shfl_xor(ps, 1, 64);
        ps += __shfl_xor(ps, 2, 64);
        ps += __shfl_xor(ps, 4, 64);
        ps += __shfl_xor(ps, 8, 64);
        const float mu = ps * (1.0f / 64.0f);
        const float d0 = h0 - mu, d1 = h1 - mu, d2 = h2 - mu, d3 = h3 - mu;
        float vs = (d0 * d0 + d1 * d1) + (d2 * d2 + d3 * d3);
        vs += __shfl_xor(vs, 1, 64);
        vs += __shfl_xor(vs, 2, 64);
        vs += __shfl_xor(vs, 4, 64);
        vs += __shfl_xor(vs, 8, 64);
        const float rstd = rsqrtf(vs * (1.0f / 64.0f) + LN_EPS);

        const int node = n0 + 4 * kb + j;
        const float dd[4] = {d0, d1, d2, d3};
#pragma unroll
        for (int c = 0; c < 4; ++c) {
            float o = dd[c] * rstd * gv[c] + btv[c];
            o = o > 0.f ? o : expm1f(o);
            if (out_f) out_f[node * D + 16 * c + row] = o;
            else       out_b[node * D + 16 * c + row] = f2h(o);
        }
    }
}

static inline size_t alignup(size_t v) { return (v + 255) & ~(size_t)255; }

extern "C" void kernel_launch(void* const* d_in, const int* in_sizes, int n_in,
                              void* d_out, int out_size, void* d_ws, size_t ws_size,
                              hipStream_t stream) {
    const float* features = (const float*)d_in[0];
    const int*   src      = (const int*)d_in[1];
    const int*   dst      = (const int*)d_in[2];
    const float* Ws       = (const float*)d_in[3];
    const float* bs       = (const float*)d_in[4];
    const float* gammas   = (const float*)d_in[5];
    const float* betas    = (const float*)d_in[6];
    float* out = (float*)d_out;

    char* ws = (char*)d_ws;
    size_t off = 0;
    int* row_ptr = (int*)(ws + off); off = alignup(off + sizeof(int) * N_NODES);
    int* deg     = (int*)(ws + off); off = alignup(off + sizeof(int) * N_NODES);
    int* bofs    = (int*)(ws + off); off = alignup(off + sizeof(int) * (size_t)NEB * BOFS_STRIDE);
    int* ebuf    = (int*)(ws + off); off = alignup(off + sizeof(int) * (size_t)NEB * EPB);
    int* ssrc    = (int*)(ws + off); off = alignup(off + sizeof(int) * (size_t)NBUCK * BCAP);
    ushort* prs  = (ushort*)(ws + off); off = alignup(off + sizeof(ushort) * (size_t)NTILES * 32);
    ushort* xbA  = (ushort*)(ws + off); off = alignup(off + sizeof(ushort) * (size_t)N_NODES * D);
    ushort* xbB  = (ushort*)(ws + off); off = alignup(off + sizeof(ushort) * (size_t)N_NODES * D);
    ushort* Wperm= (ushort*)(ws + off); off = alignup(off + sizeof(ushort) * 3 * TWO_D * D);

    // --- setup: bscat + converters in one union grid ---
    setup_kernel<<<NEB + CVT_BLOCKS, 1024, 0, stream>>>(src, dst, ebuf, bofs,
                                                        features, Ws, xbA, Wperm);
    // --- padded CSR + degree-balanced pairs ---
    bbuild_kernel<<<NBUCK, 512, 0, stream>>>(ebuf, bofs, row_ptr, deg, ssrc, prs);

    // --- 3 fused layers ---
    ushort* xin = xbA;
    ushort* xnb[3] = { xbB, xbA, nullptr };
    for (int l = 0; l < 3; ++l) {
        layer_kernel<<<NTILES, 256, 0, stream>>>(
            xin, row_ptr, deg, ssrc, prs,
            Wperm + (size_t)l * 16 * 64 * 8,
            bs + (size_t)l * D,
            gammas + (size_t)l * D,
            betas + (size_t)l * D,
            xnb[l],
            (l == 2) ? out : nullptr);
        xin = xnb[l];
    }
}

// Round 15
// 141.781 us; speedup vs baseline: 1.2859x; 1.2859x over previous
//
#include <hip/hip_runtime.h>
#include <hip/hip_bf16.h>
#include <math.h>

#define N_NODES 100000
#define N_EDGES 1600000
#define D 64
#define TWO_D 128
#define LN_EPS 1e-5f

#define BSHIFT 7                                   // 128 nodes per bucket
#define BMASK 127
#define NBUCK ((N_NODES + 127) >> BSHIFT)          // 782
#define BCAP 4096                                  // per-bucket CSR capacity (mean 2046, +45 sigma)
#define EPB 4096                                   // edges per bscat block
#define NEB ((N_EDGES + EPB - 1) / EPB)            // 391
#define BOFS_STRIDE (NBUCK + 1)
#define NTILES ((N_NODES + 63) / 64)               // 1563
#define XQ (N_NODES * D / 4)                       // float4 count for x cvt
#define WELEMS (3 * 4 * 4 * 64 * 8)                // Wperm element count
#define CVT_BLOCKS ((XQ + WELEMS + 1023) / 1024)   // 1587

typedef __attribute__((ext_vector_type(4))) float f32x4;
typedef __attribute__((ext_vector_type(8))) _Float16 h16x8;
typedef __attribute__((ext_vector_type(8))) unsigned short u16x8;

__device__ __forceinline__ unsigned short f2h(float f) {
    return __builtin_bit_cast(unsigned short, (_Float16)f);   // RNE
}
// fp16 packed max on u16 storage (v_pk_max_f16; data is NaN-free).
__device__ __forceinline__ u16x8 pkmaxh(u16x8 a, u16x8 b) {
    return __builtin_bit_cast(u16x8,
        __builtin_elementwise_max(__builtin_bit_cast(h16x8, a),
                                  __builtin_bit_cast(h16x8, b)));
}

// ---------------------------------------------------------------------------
// setup: union grid. Blocks [0, NEB) run bscat (per-block LDS sort by bucket,
// EPB=4096 -> 391 blocks fills all CUs); blocks [NEB, ..) run the fp16
// converters concurrently (cvt hides behind bscat).
// Edge record packed to int32: (src << 7) | (dst & 127); src < 2^17.
// ---------------------------------------------------------------------------
__global__ __launch_bounds__(1024) void setup_kernel(const int* __restrict__ src,
                                                     const int* __restrict__ dst,
                                                     int* __restrict__ ebuf,
                                                     int* __restrict__ bofs,
                                                     const float* __restrict__ xf,
                                                     const float* __restrict__ Ws,
                                                     ushort* __restrict__ xb,
                                                     ushort* __restrict__ Wperm) {
    if (blockIdx.x < NEB) {
        __shared__ int cnt[NBUCK];
        __shared__ int off[NBUCK];
        __shared__ int stage[EPB];
        const int e0 = blockIdx.x * EPB;
        const int nE = min(EPB, N_EDGES - e0);
        int d[4], s[4];

        for (int i = threadIdx.x; i < NBUCK; i += 1024) cnt[i] = 0;
        __syncthreads();
#pragma unroll
        for (int k = 0; k < 4; ++k) {
            const int i = threadIdx.x + k * 1024;
            if (i < nE) {
                d[k] = dst[e0 + i];
                s[k] = src[e0 + i];
                atomicAdd(&cnt[d[k] >> BSHIFT], 1);
            }
        }
        __syncthreads();
        // Hillis-Steele inclusive scan over NBUCK (<1024)
        const int v = (threadIdx.x < NBUCK) ? cnt[threadIdx.x] : 0;
        if (threadIdx.x < NBUCK) off[threadIdx.x] = v;
        __syncthreads();
        for (int o = 1; o < 1024; o <<= 1) {
            int t = 0;
            if (threadIdx.x < NBUCK && threadIdx.x >= o) t = off[threadIdx.x - o];
            __syncthreads();
            if (threadIdx.x < NBUCK) off[threadIdx.x] += t;
            __syncthreads();
        }
        if (threadIdx.x < NBUCK) {
            const int ex = off[threadIdx.x] - v;      // exclusive
            bofs[blockIdx.x * BOFS_STRIDE + threadIdx.x] = ex;
            off[threadIdx.x] = ex;
            cnt[threadIdx.x] = 0;
        }
        if (threadIdx.x == 0) bofs[blockIdx.x * BOFS_STRIDE + NBUCK] = nE;
        __syncthreads();
#pragma unroll
        for (int k = 0; k < 4; ++k) {
            const int i = threadIdx.x + k * 1024;
            if (i < nE) {
                const int b = d[k] >> BSHIFT;
                const int r = atomicAdd(&cnt[b], 1);
                stage[off[b] + r] = (s[k] << BSHIFT) | (d[k] & BMASK);
            }
        }
        __syncthreads();
        for (int i = threadIdx.x; i < nE; i += 1024)
            ebuf[e0 + i] = stage[i];
    } else {
        const int i = (blockIdx.x - NEB) * 1024 + threadIdx.x;
        if (i < XQ) {
            float4 v = ((const float4*)xf)[i];
            ushort4 o;
            o.x = f2h(v.x); o.y = f2h(v.y); o.z = f2h(v.z); o.w = f2h(v.w);
            ((ushort4*)xb)[i] = o;
        } else {
            const int k = i - XQ;
            if (k < WELEMS) {
                int j    = k & 7;
                int lane = (k >> 3) & 63;
                int c    = (k >> 9) & 3;
                int s    = (k >> 11) & 3;
                int lay  = k >> 13;
                int kk = 32 * s + 8 * (lane >> 4) + j;
                int dd = 16 * c + (lane & 15);
                Wperm[k] = f2h(Ws[((size_t)lay * TWO_D + kk) * D + dd]);
            }
        }
    }
}

// ---------------------------------------------------------------------------
// bbuild: one block per bucket (512 threads). DENSE run gather: each thread
// owns output positions pos, pos+512, ... and binary-searches rdst[] to find
// its run -> all ~2046 loads in flight. LDS counting sort -> padded CSR +
// degree-balanced pairs (fused bitonic per 64-node tile).
// ---------------------------------------------------------------------------
__global__ __launch_bounds__(512) void bbuild_kernel(const int* __restrict__ ebuf,
                                                     const int* __restrict__ bofs,
                                                     int* __restrict__ row_ptr,
                                                     int* __restrict__ deg,
                                                     int* __restrict__ ssrc,
                                                     ushort* __restrict__ pairs) {
    __shared__ int rst[NEB], rlen[NEB], rdst[NEB];
    __shared__ int stage[BCAP];
    __shared__ int stage2[BCAP];
    __shared__ int cnt[128], excl[128];
    const int b = blockIdx.x;
    const int nb0 = b << BSHIFT;

    for (int i = threadIdx.x; i < NEB; i += 512) {
        const int st = bofs[i * BOFS_STRIDE + b];
        const int en = bofs[i * BOFS_STRIDE + b + 1];
        rst[i] = st; rlen[i] = en - st;
    }
    __syncthreads();
    // scan rlen -> rdst (inclusive), NEB=391 < 512
    const int rv = (threadIdx.x < NEB) ? rlen[threadIdx.x] : 0;
    if (threadIdx.x < NEB) rdst[threadIdx.x] = rv;
    __syncthreads();
    for (int o = 1; o < 512; o <<= 1) {
        int t = 0;
        if (threadIdx.x < NEB && threadIdx.x >= o) t = rdst[threadIdx.x - o];
        __syncthreads();
        if (threadIdx.x < NEB) rdst[threadIdx.x] += t;
        __syncthreads();
    }
    const int total = rdst[NEB - 1];

    // dense gather: binary search run for each output position
    for (int pos = threadIdx.x; pos < total; pos += 512) {
        int lo = 0, hi = NEB - 1;
        while (lo < hi) {                       // first run with rdst[run] > pos
            const int mid = (lo + hi) >> 1;
            if (rdst[mid] <= pos) lo = mid + 1; else hi = mid;
        }
        const int doff = rdst[lo] - rlen[lo];
        stage[pos] = ebuf[lo * EPB + rst[lo] + (pos - doff)];
    }
    if (threadIdx.x < 128) cnt[threadIdx.x] = 0;
    __syncthreads();

    // counting sort by node-within-bucket
    for (int i = threadIdx.x; i < total; i += 512)
        atomicAdd(&cnt[stage[i] & BMASK], 1);
    __syncthreads();
    const int cv = (threadIdx.x < 128) ? cnt[threadIdx.x] : 0;
    if (threadIdx.x < 128) excl[threadIdx.x] = cv;
    __syncthreads();
    for (int o = 1; o < 128; o <<= 1) {
        int t = 0;
        if (threadIdx.x < 128 && threadIdx.x >= o) t = excl[threadIdx.x - o];
        __syncthreads();
        if (threadIdx.x < 128) excl[threadIdx.x] += t;
        __syncthreads();
    }
    const int lane = threadIdx.x & 63;
    if (threadIdx.x < 128) {
        excl[threadIdx.x] -= cv;              // exclusive
        const int node = nb0 + threadIdx.x;
        if (node < N_NODES) {
            row_ptr[node] = b * BCAP + excl[threadIdx.x];
            deg[node] = cv;
        }
        cnt[threadIdx.x] = 0;
    }

    // fused dbal: bitonic-sort each 64-node tile by degree, pair g <-> 63-g.
    if (threadIdx.x < 128) {
        const int tile = 2 * b + (threadIdx.x >> 6);
        if (tile < NTILES) {
            int key = (cv << 6) | lane;
#pragma unroll
            for (int k = 2; k <= 64; k <<= 1) {
#pragma unroll
                for (int jj = k >> 1; jj > 0; jj >>= 1) {
                    const int other = __shfl_xor(key, jj, 64);
                    const bool up = ((lane & k) == 0);
                    const bool lower = ((lane & jj) == 0);
                    key = (lower == up) ? min(key, other) : max(key, other);
                }
            }
            const int small_nl = key & 63;
            const int big_nl = __shfl(key, 63 - lane, 64) & 63;
            if (lane < 32)
                pairs[tile * 32 + lane] = (ushort)((big_nl << 6) | small_nl);
        }
    }
    __syncthreads();

    for (int i = threadIdx.x; i < total; i += 512) {
        const int p = stage[i];
        const int dl = p & BMASK;
        const int r = atomicAdd(&cnt[dl], 1);
        stage2[excl[dl] + r] = p >> BSHIFT;
    }
    __syncthreads();
    for (int i = threadIdx.x; i < total; i += 512)
        ssrc[b * BCAP + i] = stage2[i];
}

// ---------------------------------------------------------------------------
// Pipelined gather (round-13 verified form): 4-row quads, lookahead across
// quads. Peak 8 rows in flight. Tails branch-free: edge index clamps to
// cnt-1 (max idempotent).
// ---------------------------------------------------------------------------
__device__ __forceinline__ void gather_node(const u16x8* __restrict__ x8,
                                            const int* __restrict__ ssrc,
                                            int fl, int base, int beg, int end,
                                            u16x8& m) {
    if (beg >= end) return;
    int j = beg;
    int cnt = min(end - j, 8);
    int idx = ssrc[j + min(fl, cnt - 1)];

    int s0 = __shfl(idx, base, 64);
    int s1 = __shfl(idx, base + min(1, cnt - 1), 64);
    int s2 = __shfl(idx, base + min(2, cnt - 1), 64);
    int s3 = __shfl(idx, base + min(3, cnt - 1), 64);
    u16x8 a0 = x8[s0 * 8 + fl];
    u16x8 a1 = x8[s1 * 8 + fl];
    u16x8 a2 = x8[s2 * 8 + fl];
    u16x8 a3 = x8[s3 * 8 + fl];

    while (true) {
        // quad-hi of current batch (clamped duplicates when cnt <= 4)
        int s4 = __shfl(idx, base + min(4, cnt - 1), 64);
        int s5 = __shfl(idx, base + min(5, cnt - 1), 64);
        int s6 = __shfl(idx, base + min(6, cnt - 1), 64);
        int s7 = __shfl(idx, base + min(7, cnt - 1), 64);
        u16x8 b0 = x8[s4 * 8 + fl];
        u16x8 b1 = x8[s5 * 8 + fl];
        u16x8 b2 = x8[s6 * 8 + fl];
        u16x8 b3 = x8[s7 * 8 + fl];

        const int nj = j + cnt;
        const bool more = nj < end;              // group-uniform
        int ncnt = cnt, nidx = idx;
        if (more) {
            ncnt = min(end - nj, 8);
            nidx = ssrc[nj + min(fl, ncnt - 1)]; // prefetched index batch
        }

        m = pkmaxh(m, pkmaxh(pkmaxh(a0, a1), pkmaxh(a2, a3)));   // consume lo

        if (more) {                              // next batch quad-lo in flight
            int u0 = __shfl(nidx, base, 64);
            int u1 = __shfl(nidx, base + min(1, ncnt - 1), 64);
            int u2 = __shfl(nidx, base + min(2, ncnt - 1), 64);
            int u3 = __shfl(nidx, base + min(3, ncnt - 1), 64);
            a0 = x8[u0 * 8 + fl];
            a1 = x8[u1 * 8 + fl];
            a2 = x8[u2 * 8 + fl];
            a3 = x8[u3 * 8 + fl];
        }

        m = pkmaxh(m, pkmaxh(pkmaxh(b0, b1), pkmaxh(b2, b3)));   // consume hi

        if (!more) break;
        j = nj; cnt = ncnt; idx = nidx;
    }
}

// ---------------------------------------------------------------------------
// Fused layer (fp16): 64 nodes per 256-thread block; degree-balanced pairs;
// per-node pipelined gather; MFMA GEMM + bias + LN + ELU.
// ---------------------------------------------------------------------------
__global__ __launch_bounds__(256, 8) void layer_kernel(
    const ushort* __restrict__ xb,      // fp16 bits
    const int* __restrict__ row_ptr,
    const int* __restrict__ deg,
    const int* __restrict__ ssrc,
    const ushort* __restrict__ pairs,
    const ushort* __restrict__ Wperm,   // this layer's [4][4][64][8] fp16
    const float* __restrict__ bias,
    const float* __restrict__ gamma,
    const float* __restrict__ beta,
    ushort* __restrict__ out_b,         // fp16 out (layers 0,1) or nullptr
    float*  __restrict__ out_f)         // f32 out (layer 2) or nullptr
{
    __shared__ u16x8 xt[64][8];
    __shared__ u16x8 at[64][8];

    const int tid = threadIdx.x;
    const int fl = tid & 7;
    const int base = tid & 56;                 // 8-lane group base within wave
    const int grp = tid >> 3;                  // 0..31
    const u16x8* __restrict__ x8 = (const u16x8*)xb;
    const int nblk0 = blockIdx.x * 64;

    const int pr = pairs[blockIdx.x * 32 + grp];
    const int nls[2] = { pr & 63, (pr >> 6) & 63 };

#pragma unroll
    for (int q = 0; q < 2; ++q) {
        const int nl = nls[q];
        const int node = nblk0 + nl;
        if (node < N_NODES) {
            const int beg = row_ptr[node];
            const int end = beg + deg[node];

            u16x8 m;
#pragma unroll
            for (int e = 0; e < 8; ++e) m[e] = 0xFC00;   // -inf fp16
            gather_node(x8, ssrc, fl, base, beg, end, m);

            const u16x8 xs = x8[node * 8 + fl];          // load after gather
            u16x8 o;
            if (end > beg) {
                h16x8 dd = __builtin_bit_cast(h16x8, m) -
                           __builtin_bit_cast(h16x8, xs);
                h16x8 zz = 0;
                o = __builtin_bit_cast(u16x8, __builtin_elementwise_max(dd, zz));
            } else {
#pragma unroll
                for (int e = 0; e < 8; ++e) o[e] = 0;
            }
            const int slot = fl ^ (nl & 7);
            xt[nl][slot] = xs;
            at[nl][slot] = o;
        }
    }
    __syncthreads();

    // --- GEMM phase: wave per 16 nodes ---
    const int wave = tid >> 6;
    const int lane = tid & 63;
    const int n0 = nblk0 + wave * 16;
    if (n0 >= N_NODES) return;
    const int row = lane & 15;
    const int kb  = lane >> 4;
    const int nl  = wave * 16 + row;
    const int sw  = nl & 7;

    h16x8 a0 = __builtin_bit_cast(h16x8, xt[nl][kb ^ sw]);
    h16x8 a1 = __builtin_bit_cast(h16x8, xt[nl][(kb + 4) ^ sw]);
    h16x8 a2 = __builtin_bit_cast(h16x8, at[nl][kb ^ sw]);
    h16x8 a3 = __builtin_bit_cast(h16x8, at[nl][(kb + 4) ^ sw]);

    const h16x8* __restrict__ wp = (const h16x8*)Wperm;
    h16x8 wf[4][4];
#pragma unroll
    for (int s = 0; s < 4; ++s)
#pragma unroll
        for (int c = 0; c < 4; ++c)
            wf[s][c] = wp[(s * 4 + c) * 64 + lane];

    f32x4 acc[4];
#pragma unroll
    for (int c = 0; c < 4; ++c) acc[c] = (f32x4){0.f, 0.f, 0.f, 0.f};
#pragma unroll
    for (int c = 0; c < 4; ++c) {
        acc[c] = __builtin_amdgcn_mfma_f32_16x16x32_f16(a0, wf[0][c], acc[c], 0, 0, 0);
        acc[c] = __builtin_amdgcn_mfma_f32_16x16x32_f16(a1, wf[1][c], acc[c], 0, 0, 0);
        acc[c] = __builtin_amdgcn_mfma_f32_16x16x32_f16(a2, wf[2][c], acc[c], 0, 0, 0);
        acc[c] = __builtin_amdgcn_mfma_f32_16x16x32_f16(a3, wf[3][c], acc[c], 0, 0, 0);
    }

    float bv[4], gv[4], btv[4];
#pragma unroll
    for (int c = 0; c < 4; ++c) {
        const int col = 16 * c + row;
        bv[c] = bias[col]; gv[c] = gamma[col]; btv[c] = beta[col];
    }

#pragma unroll
    for (int j = 0; j < 4; ++j) {
        float h0 = acc[0][j] + bv[0];
        float h1 = acc[1][j] + bv[1];
        float h2 = acc[2][j] + bv[2];
        float h3 = acc[3][j] + bv[3];
        float ps = (h0 + h1) + (h2 + h3);
        ps += __shfl_xor(ps, 1, 64);
        ps += __shfl_xor(ps, 2, 64);
        ps += __shfl_xor(ps, 4, 64);
        ps += __shfl_xor(ps, 8, 64);
        const float mu = ps * (1.0f / 64.0f);
        const float d0 = h0 - mu, d1 = h1 - mu, d2 = h2 - mu, d3 = h3 - mu;
        float vs = (d0 * d0 + d1 * d1) + (d2 * d2 + d3 * d3);
        vs += __shfl_xor(vs, 1, 64);
        vs += __shfl_xor(vs, 2, 64);
        vs += __shfl_xor(vs, 4, 64);
        vs += __shfl_xor(vs, 8, 64);
        const float rstd = rsqrtf(vs * (1.0f / 64.0f) + LN_EPS);

        const int node = n0 + 4 * kb + j;
        const float dd[4] = {d0, d1, d2, d3};
#pragma unroll
        for (int c = 0; c < 4; ++c) {
            float o = dd[c] * rstd * gv[c] + btv[c];
            o = o > 0.f ? o : expm1f(o);
            if (out_f) out_f[node * D + 16 * c + row] = o;
            else       out_b[node * D + 16 * c + row] = f2h(o);
        }
    }
}

static inline size_t alignup(size_t v) { return (v + 255) & ~(size_t)255; }

extern "C" void kernel_launch(void* const* d_in, const int* in_sizes, int n_in,
                              void* d_out, int out_size, void* d_ws, size_t ws_size,
                              hipStream_t stream) {
    const float* features = (const float*)d_in[0];
    const int*   src      = (const int*)d_in[1];
    const int*   dst      = (const int*)d_in[2];
    const float* Ws       = (const float*)d_in[3];
    const float* bs       = (const float*)d_in[4];
    const float* gammas   = (const float*)d_in[5];
    const float* betas    = (const float*)d_in[6];
    float* out = (float*)d_out;

    char* ws = (char*)d_ws;
    size_t off = 0;
    int* row_ptr = (int*)(ws + off); off = alignup(off + sizeof(int) * N_NODES);
    int* deg     = (int*)(ws + off); off = alignup(off + sizeof(int) * N_NODES);
    int* bofs    = (int*)(ws + off); off = alignup(off + sizeof(int) * (size_t)NEB * BOFS_STRIDE);
    int* ebuf    = (int*)(ws + off); off = alignup(off + sizeof(int) * (size_t)NEB * EPB);
    int* ssrc    = (int*)(ws + off); off = alignup(off + sizeof(int) * (size_t)NBUCK * BCAP);
    ushort* prs  = (ushort*)(ws + off); off = alignup(off + sizeof(ushort) * (size_t)NTILES * 32);
    ushort* xbA  = (ushort*)(ws + off); off = alignup(off + sizeof(ushort) * (size_t)N_NODES * D);
    ushort* xbB  = (ushort*)(ws + off); off = alignup(off + sizeof(ushort) * (size_t)N_NODES * D);
    ushort* Wperm= (ushort*)(ws + off); off = alignup(off + sizeof(ushort) * 3 * TWO_D * D);

    // --- setup: bscat + converters in one union grid ---
    setup_kernel<<<NEB + CVT_BLOCKS, 1024, 0, stream>>>(src, dst, ebuf, bofs,
                                                        features, Ws, xbA, Wperm);
    // --- padded CSR + degree-balanced pairs ---
    bbuild_kernel<<<NBUCK, 512, 0, stream>>>(ebuf, bofs, row_ptr, deg, ssrc, prs);

    // --- 3 fused layers ---
    ushort* xin = xbA;
    ushort* xnb[3] = { xbB, xbA, nullptr };
    for (int l = 0; l < 3; ++l) {
        layer_kernel<<<NTILES, 256, 0, stream>>>(
            xin, row_ptr, deg, ssrc, prs,
            Wperm + (size_t)l * 16 * 64 * 8,
            bs + (size_t)l * D,
            gammas + (size_t)l * D,
            betas + (size_t)l * D,
            xnb[l],
            (l == 2) ? out : nullptr);
        xin = xnb[l];
    }
}